// Round 4
// baseline (4291.057 us; speedup 1.0000x reference)
//
#include <hip/hip_runtime.h>
#include <float.h>

#define Bz   4
#define Cz   128
#define Nz   8192
#define Kz   20
#define OUTz 128

// ---------------------------------------------------------------------------
// Kernel 1: xx[b*N+n] = sum_c x[b][c][n]^2   (unchanged)
// ---------------------------------------------------------------------------
__global__ __launch_bounds__(256) void xx_kernel(const float* __restrict__ x,
                                                 float* __restrict__ xx) {
    int t = blockIdx.x * 256 + threadIdx.x;          // 0 .. B*N-1
    int b = t >> 13;
    int n = t & (Nz - 1);
    const float* xp = x + (size_t)b * Cz * Nz + n;
    float s = 0.f;
#pragma unroll 8
    for (int c = 0; c < Cz; ++c) {
        float v = xp[(size_t)c * Nz];
        s = fmaf(v, v, s);
    }
    xx[t] = s;
}

// ---------------------------------------------------------------------------
// Kernel 2: fused pairwise-score GEMM + per-row top-20.
// Grid (N/32, B), block 256, 4 blocks/CU. Block = 32 query rows (from
// blockIdx ONLY -> wave-uniform A addresses -> s_load into SGPRs) x 256-key
// tiles. Lane <-> key (tid), acc[32] = one column of the score tile.
// Per-pair fp32 chain (ascending c, single fmaf, query*key operand order,
// 2*acc-xx) is IDENTICAL to rounds 1-3 -> bit-identical scores/selection.
//  - B operand: 1 ds_read_b32 per c, contiguous per wave -> conflict-free.
//  - staging: global float4 -> regs -> LDS, double-buffered (A/B 8KB each),
//    loads for chunk n+1 issued right after the barrier, hidden under 16
//    c-steps of FMA.
//  - score tile (32x256, 32KB) aliases both staging buffers (disjoint in
//    time; next tile's chunk 0 sits in registers during selection).
//  - selection: rotated-b32 scan (conflict-free), 32-bit masks combined via
//    shfl_xor/shfl into 4x u64 words per owner (8 owners/wave, 8 rows each),
//    extraction in ascending global j with live-wv recheck (identical final
//    set + tie behavior as serial ascending scan).
// ---------------------------------------------------------------------------
__global__ __launch_bounds__(256, 4) void knn_kernel(const float* __restrict__ x,
                                                     const float* __restrict__ xxg,
                                                     int* __restrict__ idxout) {
    const int b  = blockIdx.y;
    const int q0 = blockIdx.x * 32;

    __shared__ __align__(16) float lds[8192];   // 32KB total
    float* bufA = lds;          // 16c x 256k chunk buffer
    float* bufB = lds + 4096;   // 16c x 256k chunk buffer
    float* sc   = lds;          // 32q x 256k score tile (aliased)

    const int tid  = threadIdx.x;
    const int lane = tid & 63;
    const int wid  = tid >> 6;
    const int cg   = tid >> 6;          // staging c-group (0..3)
    const int k4   = (tid & 63) * 4;    // staging key quad

    const float* xb = x + (size_t)b * Cz * Nz;

    // top-20 state: 8 owner lanes per wave (lane<8), row rg = wid*8+lane
    float tv[Kz];
    int   ti[Kz];
#pragma unroll
    for (int s = 0; s < Kz; ++s) { tv[s] = -FLT_MAX; ti[s] = 0; }
    float wv = -FLT_MAX;
    int wslot = 0;
    const int rg = wid * 8 + (lane & 7);    // row this lane scans / owns

    float4 st0[4], st1[4];

#define LOADCHUNK(dst, kj, ch)                                                \
    {                                                                         \
        _Pragma("unroll")                                                     \
        for (int i = 0; i < 4; ++i)                                           \
            dst[i] = *(const float4*)&xb[(size_t)((ch) * 16 + cg * 4 + i) * Nz + (kj) + k4]; \
    }

#define WRITECHUNK(src, buf)                                                  \
    {                                                                         \
        _Pragma("unroll")                                                     \
        for (int i = 0; i < 4; ++i)                                           \
            *(float4*)&(buf)[(cg * 4 + i) * 256 + k4] = src[i];               \
    }

#define COMPUTECHUNK(buf, ch)                                                 \
    {                                                                         \
        _Pragma("unroll")                                                     \
        for (int cc = 0; cc < 16; ++cc) {                                     \
            float vb = (buf)[cc * 256 + tid];                                 \
            const float* ar = xb + (size_t)((ch) * 16 + cc) * Nz + q0;        \
            _Pragma("unroll")                                                 \
            for (int q = 0; q < 32; ++q)                                      \
                acc[q] = fmaf(ar[q], vb, acc[q]);                             \
        }                                                                     \
    }

#define EXTRACT(pm_, base_)                                                   \
    {                                                                         \
        unsigned long long pm = (pm_);                                        \
        while (pm) {                                                          \
            int j = __ffsll(pm) - 1;                                          \
            pm &= pm - 1;                                                     \
            int col = (base_) + j;                                            \
            float s = sc[rg * 256 + ((col + rg) & 255)];                      \
            if (s > wv) {                                                     \
                int gj = kj0 + col;                                           \
                _Pragma("unroll")                                             \
                for (int s2 = 0; s2 < Kz; ++s2) {                             \
                    bool hit = (s2 == wslot);                                 \
                    tv[s2] = hit ? s : tv[s2];                                \
                    ti[s2] = hit ? gj : ti[s2];                               \
                }                                                             \
                wv = tv[0]; wslot = 0;                                        \
                _Pragma("unroll")                                             \
                for (int s2 = 1; s2 < Kz; ++s2)                               \
                    if (tv[s2] < wv) { wv = tv[s2]; wslot = s2; }             \
            }                                                                 \
        }                                                                     \
    }

    // prologue: tile 0, chunk 0
    LOADCHUNK(st0, 0, 0);

    for (int kt = 0; kt < Nz / 256; ++kt) {
        const int kj0  = kt * 256;
        const int kj0n = ((kt + 1) & (Nz / 256 - 1)) * 256;

        float acc[32];
#pragma unroll
        for (int q = 0; q < 32; ++q) acc[q] = 0.f;

#pragma unroll
        for (int ch2 = 0; ch2 < 4; ++ch2) {
            const int e = 2 * ch2;
            // even chunk -> bufA
            WRITECHUNK(st0, bufA);
            __syncthreads();
            LOADCHUNK(st1, kj0, e + 1);
            COMPUTECHUNK(bufA, e);
            // odd chunk -> bufB
            WRITECHUNK(st1, bufB);
            __syncthreads();
            if (e == 6) { LOADCHUNK(st0, kj0n, 0); }
            else        { LOADCHUNK(st0, kj0, e + 2); }
            COMPUTECHUNK(bufB, e + 1);
        }
        __syncthreads();   // all compute reads of bufA/bufB done

        // scores -> sc (rotated cols): row q, col tid
        {
            float xxv = xxg[b * Nz + kj0 + tid];
#pragma unroll
            for (int q = 0; q < 32; ++q)
                sc[q * 256 + ((tid + q) & 255)] = 2.f * acc[q] - xxv;
        }
        __syncthreads();

        // scan: lane = (row rg, part = lane>>3), 32 cols per lane
        {
            float wvb = __shfl(wv, lane & 7);
            const int part = lane >> 3;
            unsigned m = 0;
#pragma unroll
            for (int i = 0; i < 32; ++i) {
                int col = part * 32 + i;
                float s = sc[rg * 256 + ((col + rg) & 255)];
                m |= (unsigned)(s > wvb) << i;
            }
            unsigned long long f = (unsigned long long)m << (32 * (part & 1));
            f |= __shfl_xor(f, 8);
            unsigned long long w0 = __shfl(f, (lane & 7));
            unsigned long long w1 = __shfl(f, 16 + (lane & 7));
            unsigned long long w2 = __shfl(f, 32 + (lane & 7));
            unsigned long long w3 = __shfl(f, 48 + (lane & 7));
            if (lane < 8) {
                EXTRACT(w0, 0);
                EXTRACT(w1, 64);
                EXTRACT(w2, 128);
                EXTRACT(w3, 192);
            }
        }
        __syncthreads();   // selection reads done before next chunk write
    }

    if (lane < 8) {
        size_t base = ((size_t)b * Nz + q0 + rg) * Kz;
#pragma unroll
        for (int s = 0; s < Kz; ++s) idxout[base + s] = ti[s];
    }
#undef LOADCHUNK
#undef WRITECHUNK
#undef COMPUTECHUNK
#undef EXTRACT
}

// ---------------------------------------------------------------------------
// Kernel 3: Y[p][o'] (unchanged)
// ---------------------------------------------------------------------------
__global__ __launch_bounds__(256) void feat_kernel(const float* __restrict__ x,
                                                   const float* __restrict__ W,
                                                   const float* __restrict__ bias,
                                                   float* __restrict__ Y) {
    const int gp0 = blockIdx.x * 64;         // global point index (b*N+n)
    const int b   = gp0 >> 13;
    const int n0  = gp0 & (Nz - 1);
    const int o0  = blockIdx.y * 64;

    __shared__ __align__(16) float xt[128 * 64];   // [c][p]
    __shared__ __align__(16) float wt[128 * 64];   // [c][o']

    const int tid = threadIdx.x;
    const int tx  = tid & 15;
    const int ty  = tid >> 4;

    {
        int li = tid & 63;
        int c0 = tid >> 6;
        const float* xbp = x + (size_t)b * Cz * Nz + n0;
#pragma unroll
        for (int rep = 0; rep < 32; ++rep) {
            int c = c0 + rep * 4;
            xt[c * 64 + li] = xbp[(size_t)c * Nz + li];
        }
    }
    {
        int lo = tid & 63;
        int c0 = tid >> 6;
        int oo = o0 + lo;
#pragma unroll
        for (int rep = 0; rep < 32; ++rep) {
            int c = c0 + rep * 4;
            float w;
            if (oo < 128) w = W[oo * 256 + c] + W[oo * 256 + 128 + c];
            else          w = W[(oo - 128) * 256 + 128 + c];
            wt[c * 64 + lo] = w;
        }
    }
    __syncthreads();

    float acc[4][4];
#pragma unroll
    for (int di = 0; di < 4; ++di)
#pragma unroll
        for (int dj = 0; dj < 4; ++dj) acc[di][dj] = 0.f;

    const int aoff = ty * 4;
    const int boff = tx * 4;
#pragma unroll 8
    for (int c = 0; c < 128; ++c) {
        float4 a  = *(const float4*)&xt[c * 64 + aoff];
        float4 ww = *(const float4*)&wt[c * 64 + boff];
        float av[4] = {a.x, a.y, a.z, a.w};
        float wvv[4] = {ww.x, ww.y, ww.z, ww.w};
#pragma unroll
        for (int di = 0; di < 4; ++di)
#pragma unroll
            for (int dj = 0; dj < 4; ++dj)
                acc[di][dj] = fmaf(av[di], wvv[dj], acc[di][dj]);
    }

    float4 bv = make_float4(0.f, 0.f, 0.f, 0.f);
    if (o0 < 128) bv = *(const float4*)&bias[o0 + tx * 4];
#pragma unroll
    for (int di = 0; di < 4; ++di) {
        float4 r;
        r.x = acc[di][0] + bv.x;
        r.y = acc[di][1] + bv.y;
        r.z = acc[di][2] + bv.z;
        r.w = acc[di][3] + bv.w;
        *(float4*)&Y[(size_t)(gp0 + ty * 4 + di) * 256 + o0 + tx * 4] = r;
    }
}

// ---------------------------------------------------------------------------
// Kernel 4: out[b][o][n] = relu(u[n][o] - min_j v[idx[n][j]][o])  (unchanged)
// ---------------------------------------------------------------------------
__global__ __launch_bounds__(256) void gather_kernel(const int* __restrict__ idxg,
                                                     const float* __restrict__ Y,
                                                     float* __restrict__ out) {
    const int gp0 = blockIdx.x * 64;
    const int b   = gp0 >> 13;
    const int n0  = gp0 & (Nz - 1);

    __shared__ int lidx[64 * 21];
    const int tid = threadIdx.x;
    for (int t = tid; t < 64 * Kz; t += 256) {
        int p = t / Kz, j = t - p * Kz;
        lidx[p * 21 + j] = idxg[(size_t)(gp0 + p) * Kz + j];
    }
    __syncthreads();

    const int p  = tid & 63;
    const int o0 = (tid >> 6) * 32;

    float mn[32];
#pragma unroll
    for (int q = 0; q < 32; ++q) mn[q] = FLT_MAX;

    for (int j = 0; j < Kz; ++j) {
        int m = lidx[p * 21 + j];
        const float4* vr =
            (const float4*)(Y + (size_t)(b * Nz + m) * 256 + 128 + o0);
#pragma unroll
        for (int q = 0; q < 8; ++q) {
            float4 v4 = vr[q];
            mn[4 * q + 0] = fminf(mn[4 * q + 0], v4.x);
            mn[4 * q + 1] = fminf(mn[4 * q + 1], v4.y);
            mn[4 * q + 2] = fminf(mn[4 * q + 2], v4.z);
            mn[4 * q + 3] = fminf(mn[4 * q + 3], v4.w);
        }
    }

    const float4* ur = (const float4*)(Y + (size_t)(gp0 + p) * 256 + o0);
#pragma unroll
    for (int q = 0; q < 8; ++q) {
        float4 u4 = ur[q];
        float r0 = fmaxf(u4.x - mn[4 * q + 0], 0.f);
        float r1 = fmaxf(u4.y - mn[4 * q + 1], 0.f);
        float r2 = fmaxf(u4.z - mn[4 * q + 2], 0.f);
        float r3 = fmaxf(u4.w - mn[4 * q + 3], 0.f);
        size_t ob = ((size_t)b * OUTz + o0 + 4 * q) * Nz + n0 + p;
        out[ob + 0 * Nz] = r0;
        out[ob + 1 * Nz] = r1;
        out[ob + 2 * Nz] = r2;
        out[ob + 3 * Nz] = r3;
    }
}

// ---------------------------------------------------------------------------
extern "C" void kernel_launch(void* const* d_in, const int* in_sizes, int n_in,
                              void* d_out, int out_size, void* d_ws, size_t ws_size,
                              hipStream_t stream) {
    const float* x    = (const float*)d_in[0];
    const float* W    = (const float*)d_in[1];
    const float* bias = (const float*)d_in[2];
    float* out = (float*)d_out;

    char* ws = (char*)d_ws;
    float* xx  = (float*)ws;                       // 128KB  @ 0
    int*   idx = (int*)(ws + (1 << 17));           // 2.5MB  @ 128KB
    float* Y   = (float*)(ws + (4 << 20));         // 32MB   @ 4MB

    xx_kernel<<<dim3(Bz * Nz / 256), dim3(256), 0, stream>>>(x, xx);

    knn_kernel<<<dim3(Nz / 32, Bz), dim3(256), 0, stream>>>(x, xx, idx);

    feat_kernel<<<dim3(Bz * Nz / 64, 4), dim3(256), 0, stream>>>(x, W, bias, Y);

    gather_kernel<<<dim3(Bz * Nz / 64), dim3(256), 0, stream>>>(idx, Y, out);
}

// Round 5
// 2093.889 us; speedup vs baseline: 2.0493x; 2.0493x over previous
//
#include <hip/hip_runtime.h>
#include <float.h>

#define Bz   4
#define Cz   128
#define Nz   8192
#define Kz   20
#define OUTz 128

// ---------------------------------------------------------------------------
// Kernel 1: xx[b*N+n] = sum_c x[b][c][n]^2   (unchanged)
// ---------------------------------------------------------------------------
__global__ __launch_bounds__(256) void xx_kernel(const float* __restrict__ x,
                                                 float* __restrict__ xx) {
    int t = blockIdx.x * 256 + threadIdx.x;          // 0 .. B*N-1
    int b = t >> 13;
    int n = t & (Nz - 1);
    const float* xp = x + (size_t)b * Cz * Nz + n;
    float s = 0.f;
#pragma unroll 8
    for (int c = 0; c < Cz; ++c) {
        float v = xp[(size_t)c * Nz];
        s = fmaf(v, v, s);
    }
    xx[t] = s;
}

// ---------------------------------------------------------------------------
// Kernel 2: fused pairwise-score GEMM + per-row top-20.
// 1-D grid 512, block 256. XCD swizzle: b=(bid&7)>>1 -> each XCD works on one
// batch -> x[b] (4MB) L2-resident. Block tile: 64 queries x 256-key tiles,
// per-thread 8x8 (tx=tid&31 -> key octet, ty=tid>>5 -> query octet).
// A-tile (64q x 128c, 32KB) LDS-resident for the whole block; B chunks
// (8c x 256k, 8KB) double-buffered via registers; score tile 64x128 (32KB)
// processed in two 128-col phases. LDS total exactly 80KB -> 2 blocks/CU.
// Per-pair fp32 chain (ascending c, single fmaf(query,key,acc), 2*acc-xx,
// ascending-j strict-> selection) IDENTICAL to rounds 1-4 -> bit-identical.
// #pragma unroll 1 on chunk/tile loops keeps the hot body ~8KB (I$-friendly).
// ---------------------------------------------------------------------------
__global__ __launch_bounds__(256, 2) void knn_kernel(const float* __restrict__ x,
                                                     const float* __restrict__ xxg,
                                                     int* __restrict__ idxout) {
    const int bid  = blockIdx.x;
    const int b    = (bid & 7) >> 1;
    const int qblk = ((bid >> 3) << 1) | (bid & 1);
    const int q0   = qblk * 64;

    __shared__ __align__(16) float Ald[128 * 64];   // 32KB [c][q]
    __shared__ __align__(16) float bufA[8 * 256];   // 8KB  [c][k]
    __shared__ __align__(16) float bufB[8 * 256];   // 8KB  [c][k]
    __shared__ __align__(16) float sc[64 * 128];    // 32KB [q][col rot]

    const int tid  = threadIdx.x;
    const int tx   = tid & 31;      // key octet
    const int ty   = tid >> 5;      // query octet (also staging c-row)
    const int lane = tid & 63;
    const int wid  = tid >> 6;

    const float* xb = x + (size_t)b * Cz * Nz;

    // stage A once: Ald[c][q] = x[b][c][q0+q]
    {
        int q4 = (tid & 15) * 4;
        int c0 = tid >> 4;          // 0..15
#pragma unroll
        for (int rep = 0; rep < 8; ++rep) {
            int c = c0 + rep * 16;
            *(float4*)&Ald[c * 64 + q4] =
                *(const float4*)&xb[(size_t)c * Nz + q0 + q4];
        }
    }
    // visibility covered by the first chunk's __syncthreads

    // top-20 state: owner = lane<16 of each wave, row orow
    float tv[Kz];
    int   ti[Kz];
#pragma unroll
    for (int s = 0; s < Kz; ++s) { tv[s] = -FLT_MAX; ti[s] = 0; }
    float wv = -FLT_MAX;
    int wslot = 0;
    const int orow = wid * 16 + lane;            // owner row (lane<16)
    const int srow = wid * 16 + (lane & 15);     // scanned row (all lanes)
    const int part = lane >> 4;                  // 32-col part

    float4 st0[2], st1[2];

#define LOADCHUNK(dst, kj, ch)                                                \
    {                                                                         \
        _Pragma("unroll")                                                     \
        for (int i = 0; i < 2; ++i)                                           \
            dst[i] = *(const float4*)&xb[(size_t)((ch) * 8 + ty) * Nz + (kj) + tx * 4 + i * 128]; \
    }

#define WRITECHUNK(src, buf)                                                  \
    {                                                                         \
        _Pragma("unroll")                                                     \
        for (int i = 0; i < 2; ++i)                                           \
            *(float4*)&(buf)[ty * 256 + tx * 4 + i * 128] = src[i];           \
    }

#define COMPUTECHUNK(buf, ch)                                                 \
    {                                                                         \
        _Pragma("unroll")                                                     \
        for (int cc = 0; cc < 8; ++cc) {                                      \
            float4 a0 = *(const float4*)&Ald[((ch) * 8 + cc) * 64 + ty * 8];  \
            float4 a1 = *(const float4*)&Ald[((ch) * 8 + cc) * 64 + ty * 8 + 4]; \
            float4 b0 = *(const float4*)&(buf)[cc * 256 + tx * 8];            \
            float4 b1 = *(const float4*)&(buf)[cc * 256 + tx * 8 + 4];        \
            float av[8] = {a0.x, a0.y, a0.z, a0.w, a1.x, a1.y, a1.z, a1.w};   \
            float bv[8] = {b0.x, b0.y, b0.z, b0.w, b1.x, b1.y, b1.z, b1.w};   \
            _Pragma("unroll")                                                 \
            for (int q = 0; q < 8; ++q) {                                     \
                _Pragma("unroll")                                             \
                for (int k = 0; k < 8; ++k)                                   \
                    acc[q][k] = fmaf(av[q], bv[k], acc[q][k]);                \
            }                                                                 \
        }                                                                     \
    }

#define EXTRACT(pm_, cloc_, gbase_)                                           \
    {                                                                         \
        unsigned long long pm = (pm_);                                        \
        while (pm) {                                                          \
            int j = __ffsll(pm) - 1;                                          \
            pm &= pm - 1;                                                     \
            int cl = (cloc_) + j;                                             \
            float s = sc[orow * 128 + ((cl + 4 * orow) & 127)];               \
            if (s > wv) {                                                     \
                int gj = (gbase_) + j;                                        \
                _Pragma("unroll")                                             \
                for (int s2 = 0; s2 < Kz; ++s2) {                             \
                    bool hit = (s2 == wslot);                                 \
                    tv[s2] = hit ? s : tv[s2];                                \
                    ti[s2] = hit ? gj : ti[s2];                               \
                }                                                             \
                wv = tv[0]; wslot = 0;                                        \
                _Pragma("unroll")                                             \
                for (int s2 = 1; s2 < Kz; ++s2)                               \
                    if (tv[s2] < wv) { wv = tv[s2]; wslot = s2; }             \
            }                                                                 \
        }                                                                     \
    }

    // prologue: tile 0, chunk 0
    LOADCHUNK(st0, 0, 0);

#pragma unroll 1
    for (int kt = 0; kt < Nz / 256; ++kt) {
        const int kj0 = kt * 256;
        const int kjn = ((kt + 1) & (Nz / 256 - 1)) * 256;

        float acc[8][8];
#pragma unroll
        for (int q = 0; q < 8; ++q)
#pragma unroll
            for (int k = 0; k < 8; ++k) acc[q][k] = 0.f;

#pragma unroll 1
        for (int cp = 0; cp < 8; ++cp) {
            const int e = 2 * cp;
            WRITECHUNK(st0, bufA);
            __syncthreads();
            LOADCHUNK(st1, kj0, e + 1);
            COMPUTECHUNK(bufA, e);
            WRITECHUNK(st1, bufB);
            __syncthreads();
            if (e == 14) { LOADCHUNK(st0, kjn, 0); }
            else         { LOADCHUNK(st0, kj0, e + 2); }
            COMPUTECHUNK(bufB, e + 1);
        }

        // ---- selection: two 128-col phases ----
        float4 xxlo = *(const float4*)&xxg[b * Nz + kj0 + tx * 8];
        float4 xxhi = *(const float4*)&xxg[b * Nz + kj0 + tx * 8 + 4];
        float xxa[8] = {xxlo.x, xxlo.y, xxlo.z, xxlo.w,
                        xxhi.x, xxhi.y, xxhi.z, xxhi.w};
        const int hmy  = tx >> 4;           // which phase my cols land in
        const int colb = (tx & 15) * 8;     // col base within the phase

#pragma unroll
        for (int h = 0; h < 2; ++h) {
            if (h) __syncthreads();         // phase-0 extract done before rewrite
            if (hmy == h) {
#pragma unroll
                for (int dq = 0; dq < 8; ++dq) {
                    int r = ty * 8 + dq;
                    float4 w0, w1;
                    w0.x = 2.f * acc[dq][0] - xxa[0];
                    w0.y = 2.f * acc[dq][1] - xxa[1];
                    w0.z = 2.f * acc[dq][2] - xxa[2];
                    w0.w = 2.f * acc[dq][3] - xxa[3];
                    w1.x = 2.f * acc[dq][4] - xxa[4];
                    w1.y = 2.f * acc[dq][5] - xxa[5];
                    w1.z = 2.f * acc[dq][6] - xxa[6];
                    w1.w = 2.f * acc[dq][7] - xxa[7];
                    *(float4*)&sc[r * 128 + ((colb + 4 * r) & 127)]     = w0;
                    *(float4*)&sc[r * 128 + ((colb + 4 + 4 * r) & 127)] = w1;
                }
            }
            __syncthreads();

            // scan: lane (srow, part) covers 32 cols
            float wvb = __shfl(wv, lane & 15);
            unsigned m = 0;
#pragma unroll
            for (int g = 0; g < 8; ++g) {
                int col = part * 32 + g * 4;
                float4 v = *(const float4*)&sc[srow * 128 + ((col + 4 * srow) & 127)];
                m |= (unsigned)(v.x > wvb) << (4 * g + 0);
                m |= (unsigned)(v.y > wvb) << (4 * g + 1);
                m |= (unsigned)(v.z > wvb) << (4 * g + 2);
                m |= (unsigned)(v.w > wvb) << (4 * g + 3);
            }
            unsigned long long f = (unsigned long long)m << (32 * (part & 1));
            f |= __shfl_xor(f, 16);
            unsigned long long whi = __shfl(f, 32 + (lane & 15));
            if (lane < 16) {
                EXTRACT(f,   0,  kj0 + h * 128);
                EXTRACT(whi, 64, kj0 + h * 128 + 64);
            }
        }
        // no trailing sync needed: next writes touch bufA/bufB, not sc;
        // sc is next written only after 16 chunk barriers.
    }

    if (lane < 16) {
        size_t base = ((size_t)b * Nz + q0 + orow) * Kz;
#pragma unroll
        for (int s = 0; s < Kz; ++s) idxout[base + s] = ti[s];
    }
#undef LOADCHUNK
#undef WRITECHUNK
#undef COMPUTECHUNK
#undef EXTRACT
}

// ---------------------------------------------------------------------------
// Kernel 3: Y[p][o'] (unchanged)
// ---------------------------------------------------------------------------
__global__ __launch_bounds__(256) void feat_kernel(const float* __restrict__ x,
                                                   const float* __restrict__ W,
                                                   const float* __restrict__ bias,
                                                   float* __restrict__ Y) {
    const int gp0 = blockIdx.x * 64;         // global point index (b*N+n)
    const int b   = gp0 >> 13;
    const int n0  = gp0 & (Nz - 1);
    const int o0  = blockIdx.y * 64;

    __shared__ __align__(16) float xt[128 * 64];   // [c][p]
    __shared__ __align__(16) float wt[128 * 64];   // [c][o']

    const int tid = threadIdx.x;
    const int tx  = tid & 15;
    const int ty  = tid >> 4;

    {
        int li = tid & 63;
        int c0 = tid >> 6;
        const float* xbp = x + (size_t)b * Cz * Nz + n0;
#pragma unroll
        for (int rep = 0; rep < 32; ++rep) {
            int c = c0 + rep * 4;
            xt[c * 64 + li] = xbp[(size_t)c * Nz + li];
        }
    }
    {
        int lo = tid & 63;
        int c0 = tid >> 6;
        int oo = o0 + lo;
#pragma unroll
        for (int rep = 0; rep < 32; ++rep) {
            int c = c0 + rep * 4;
            float w;
            if (oo < 128) w = W[oo * 256 + c] + W[oo * 256 + 128 + c];
            else          w = W[(oo - 128) * 256 + 128 + c];
            wt[c * 64 + lo] = w;
        }
    }
    __syncthreads();

    float acc[4][4];
#pragma unroll
    for (int di = 0; di < 4; ++di)
#pragma unroll
        for (int dj = 0; dj < 4; ++dj) acc[di][dj] = 0.f;

    const int aoff = ty * 4;
    const int boff = tx * 4;
#pragma unroll 8
    for (int c = 0; c < 128; ++c) {
        float4 a  = *(const float4*)&xt[c * 64 + aoff];
        float4 ww = *(const float4*)&wt[c * 64 + boff];
        float av[4] = {a.x, a.y, a.z, a.w};
        float wvv[4] = {ww.x, ww.y, ww.z, ww.w};
#pragma unroll
        for (int di = 0; di < 4; ++di)
#pragma unroll
            for (int dj = 0; dj < 4; ++dj)
                acc[di][dj] = fmaf(av[di], wvv[dj], acc[di][dj]);
    }

    float4 bv = make_float4(0.f, 0.f, 0.f, 0.f);
    if (o0 < 128) bv = *(const float4*)&bias[o0 + tx * 4];
#pragma unroll
    for (int di = 0; di < 4; ++di) {
        float4 r;
        r.x = acc[di][0] + bv.x;
        r.y = acc[di][1] + bv.y;
        r.z = acc[di][2] + bv.z;
        r.w = acc[di][3] + bv.w;
        *(float4*)&Y[(size_t)(gp0 + ty * 4 + di) * 256 + o0 + tx * 4] = r;
    }
}

// ---------------------------------------------------------------------------
// Kernel 4: out[b][o][n] = relu(u[n][o] - min_j v[idx[n][j]][o])  (unchanged)
// ---------------------------------------------------------------------------
__global__ __launch_bounds__(256) void gather_kernel(const int* __restrict__ idxg,
                                                     const float* __restrict__ Y,
                                                     float* __restrict__ out) {
    const int gp0 = blockIdx.x * 64;
    const int b   = gp0 >> 13;
    const int n0  = gp0 & (Nz - 1);

    __shared__ int lidx[64 * 21];
    const int tid = threadIdx.x;
    for (int t = tid; t < 64 * Kz; t += 256) {
        int p = t / Kz, j = t - p * Kz;
        lidx[p * 21 + j] = idxg[(size_t)(gp0 + p) * Kz + j];
    }
    __syncthreads();

    const int p  = tid & 63;
    const int o0 = (tid >> 6) * 32;

    float mn[32];
#pragma unroll
    for (int q = 0; q < 32; ++q) mn[q] = FLT_MAX;

    for (int j = 0; j < Kz; ++j) {
        int m = lidx[p * 21 + j];
        const float4* vr =
            (const float4*)(Y + (size_t)(b * Nz + m) * 256 + 128 + o0);
#pragma unroll
        for (int q = 0; q < 8; ++q) {
            float4 v4 = vr[q];
            mn[4 * q + 0] = fminf(mn[4 * q + 0], v4.x);
            mn[4 * q + 1] = fminf(mn[4 * q + 1], v4.y);
            mn[4 * q + 2] = fminf(mn[4 * q + 2], v4.z);
            mn[4 * q + 3] = fminf(mn[4 * q + 3], v4.w);
        }
    }

    const float4* ur = (const float4*)(Y + (size_t)(gp0 + p) * 256 + o0);
#pragma unroll
    for (int q = 0; q < 8; ++q) {
        float4 u4 = ur[q];
        float r0 = fmaxf(u4.x - mn[4 * q + 0], 0.f);
        float r1 = fmaxf(u4.y - mn[4 * q + 1], 0.f);
        float r2 = fmaxf(u4.z - mn[4 * q + 2], 0.f);
        float r3 = fmaxf(u4.w - mn[4 * q + 3], 0.f);
        size_t ob = ((size_t)b * OUTz + o0 + 4 * q) * Nz + n0 + p;
        out[ob + 0 * Nz] = r0;
        out[ob + 1 * Nz] = r1;
        out[ob + 2 * Nz] = r2;
        out[ob + 3 * Nz] = r3;
    }
}

// ---------------------------------------------------------------------------
extern "C" void kernel_launch(void* const* d_in, const int* in_sizes, int n_in,
                              void* d_out, int out_size, void* d_ws, size_t ws_size,
                              hipStream_t stream) {
    const float* x    = (const float*)d_in[0];
    const float* W    = (const float*)d_in[1];
    const float* bias = (const float*)d_in[2];
    float* out = (float*)d_out;

    char* ws = (char*)d_ws;
    float* xx  = (float*)ws;                       // 128KB  @ 0
    int*   idx = (int*)(ws + (1 << 17));           // 2.5MB  @ 128KB
    float* Y   = (float*)(ws + (4 << 20));         // 32MB   @ 4MB

    xx_kernel<<<dim3(Bz * Nz / 256), dim3(256), 0, stream>>>(x, xx);

    knn_kernel<<<dim3(512), dim3(256), 0, stream>>>(x, xx, idx);

    feat_kernel<<<dim3(Bz * Nz / 64, 4), dim3(256), 0, stream>>>(x, W, bias, Y);

    gather_kernel<<<dim3(Bz * Nz / 64), dim3(256), 0, stream>>>(idx, Y, out);
}

// Round 6
// 1747.770 us; speedup vs baseline: 2.4552x; 1.1980x over previous
//
#include <hip/hip_runtime.h>
#include <float.h>

#define Bz   4
#define Cz   128
#define Nz   8192
#define Kz   20
#define OUTz 128

// ---------------------------------------------------------------------------
// Kernel 1: xx[b*N+n] = sum_c x[b][c][n]^2   (unchanged)
// ---------------------------------------------------------------------------
__global__ __launch_bounds__(256) void xx_kernel(const float* __restrict__ x,
                                                 float* __restrict__ xx) {
    int t = blockIdx.x * 256 + threadIdx.x;          // 0 .. B*N-1
    int b = t >> 13;
    int n = t & (Nz - 1);
    const float* xp = x + (size_t)b * Cz * Nz + n;
    float s = 0.f;
#pragma unroll 8
    for (int c = 0; c < Cz; ++c) {
        float v = xp[(size_t)c * Nz];
        s = fmaf(v, v, s);
    }
    xx[t] = s;
}

// ---------------------------------------------------------------------------
// Kernel 2: fused pairwise-score GEMM + per-row top-20.
// Grid (N/64, B) 2-D (proven L2-friendly dispatch order), block 256.
// Block tile: 64 queries x 256-key tiles, per-thread 8x8.
// Thread (tx=tid&31, ty=tid>>5) owns queries ty*8..+7 and keys
// {tx*4..+3, 128+tx*4..+3}  <- split pattern makes every b128 LDS read
// conflict-free (16-lane phases cover banks 0..31 exactly).
// A-tile (64q x 128c, 32KB) LDS-resident; B chunks (8c x 256k, 8KB) double-
// buffered; score tile 64x128 (32KB) separate. LDS 80KB -> 2 blocks/CU.
// NO launch_bounds VGPR cap: rounds 4/5 showed (256,k) caps VGPRs at 256/k
// and forces acc spills to scratch (WRITE_SIZE 1.5-2.3GB). LDS already caps
// occupancy at 2 blocks/CU, so uncapped VGPR (~160) costs nothing.
// Per-pair fp32 chain (ascending c, single fmaf(query,key,acc), 2*acc-xx,
// ascending-j strict-> selection) IDENTICAL to rounds 1-5 -> bit-identical.
// ---------------------------------------------------------------------------
__global__ __launch_bounds__(256) void knn_kernel(const float* __restrict__ x,
                                                  const float* __restrict__ xxg,
                                                  int* __restrict__ idxout) {
    const int b  = blockIdx.y;
    const int q0 = blockIdx.x * 64;

    __shared__ __align__(16) float Ald[128 * 64];   // 32KB [c][q]
    __shared__ __align__(16) float bufA[8 * 256];   // 8KB  [c][k]
    __shared__ __align__(16) float bufB[8 * 256];   // 8KB  [c][k]
    __shared__ __align__(16) float sc[64 * 128];    // 32KB [q][col rot]

    const int tid  = threadIdx.x;
    const int tx   = tid & 31;      // key group
    const int ty   = tid >> 5;      // query octet (also staging c-row)
    const int lane = tid & 63;
    const int wid  = tid >> 6;

    const float* xb = x + (size_t)b * Cz * Nz;

    // stage A once: Ald[c][q] = x[b][c][q0+q]
    {
        int q4 = (tid & 15) * 4;
        int c0 = tid >> 4;          // 0..15
#pragma unroll
        for (int rep = 0; rep < 8; ++rep) {
            int c = c0 + rep * 16;
            *(float4*)&Ald[c * 64 + q4] =
                *(const float4*)&xb[(size_t)c * Nz + q0 + q4];
        }
    }
    // visibility covered by the first chunk's __syncthreads

    // top-20 state: owner = lane<16 of each wave, row orow
    float tv[Kz];
    int   ti[Kz];
#pragma unroll
    for (int s = 0; s < Kz; ++s) { tv[s] = -FLT_MAX; ti[s] = 0; }
    float wv = -FLT_MAX;
    int wslot = 0;
    const int orow = wid * 16 + lane;            // owner row (lane<16)
    const int srow = wid * 16 + (lane & 15);     // scanned row (all lanes)
    const int part = lane >> 4;                  // 32-col part

    float4 st0[2], st1[2];

#define LOADCHUNK(dst, kj, ch)                                                \
    {                                                                         \
        _Pragma("unroll")                                                     \
        for (int i = 0; i < 2; ++i)                                           \
            dst[i] = *(const float4*)&xb[(size_t)((ch) * 8 + ty) * Nz + (kj) + tx * 4 + i * 128]; \
    }

#define WRITECHUNK(src, buf)                                                  \
    {                                                                         \
        _Pragma("unroll")                                                     \
        for (int i = 0; i < 2; ++i)                                           \
            *(float4*)&(buf)[ty * 256 + tx * 4 + i * 128] = src[i];           \
    }

#define COMPUTECHUNK(buf, ch)                                                 \
    {                                                                         \
        _Pragma("unroll")                                                     \
        for (int cc = 0; cc < 8; ++cc) {                                      \
            float4 a0 = *(const float4*)&Ald[((ch) * 8 + cc) * 64 + ty * 8];  \
            float4 a1 = *(const float4*)&Ald[((ch) * 8 + cc) * 64 + ty * 8 + 4]; \
            float4 b0 = *(const float4*)&(buf)[cc * 256 + tx * 4];            \
            float4 b1 = *(const float4*)&(buf)[cc * 256 + 128 + tx * 4];      \
            float av[8] = {a0.x, a0.y, a0.z, a0.w, a1.x, a1.y, a1.z, a1.w};   \
            float bv[8] = {b0.x, b0.y, b0.z, b0.w, b1.x, b1.y, b1.z, b1.w};   \
            _Pragma("unroll")                                                 \
            for (int q = 0; q < 8; ++q) {                                     \
                _Pragma("unroll")                                             \
                for (int k = 0; k < 8; ++k)                                   \
                    acc[q][k] = fmaf(av[q], bv[k], acc[q][k]);                \
            }                                                                 \
        }                                                                     \
    }

#define EXTRACT(pm_, cloc_, gbase_)                                           \
    {                                                                         \
        unsigned long long pm = (pm_);                                        \
        while (pm) {                                                          \
            int j = __ffsll(pm) - 1;                                          \
            pm &= pm - 1;                                                     \
            int cl = (cloc_) + j;                                             \
            float s = sc[orow * 128 + ((cl + 4 * orow) & 127)];               \
            if (s > wv) {                                                     \
                int gj = (gbase_) + j;                                        \
                _Pragma("unroll")                                             \
                for (int s2 = 0; s2 < Kz; ++s2) {                             \
                    bool hit = (s2 == wslot);                                 \
                    tv[s2] = hit ? s : tv[s2];                                \
                    ti[s2] = hit ? gj : ti[s2];                               \
                }                                                             \
                wv = tv[0]; wslot = 0;                                        \
                _Pragma("unroll")                                             \
                for (int s2 = 1; s2 < Kz; ++s2)                               \
                    if (tv[s2] < wv) { wv = tv[s2]; wslot = s2; }             \
            }                                                                 \
        }                                                                     \
    }

    // prologue: tile 0, chunk 0
    LOADCHUNK(st0, 0, 0);

#pragma unroll 1
    for (int kt = 0; kt < Nz / 256; ++kt) {
        const int kj0 = kt * 256;
        const int kjn = ((kt + 1) & (Nz / 256 - 1)) * 256;

        float acc[8][8];
#pragma unroll
        for (int q = 0; q < 8; ++q)
#pragma unroll
            for (int k = 0; k < 8; ++k) acc[q][k] = 0.f;

#pragma unroll 1
        for (int cp = 0; cp < 8; ++cp) {
            const int e = 2 * cp;
            WRITECHUNK(st0, bufA);
            __syncthreads();
            LOADCHUNK(st1, kj0, e + 1);
            COMPUTECHUNK(bufA, e);
            WRITECHUNK(st1, bufB);
            __syncthreads();
            if (e == 14) { LOADCHUNK(st0, kjn, 0); }
            else         { LOADCHUNK(st0, kj0, e + 2); }
            COMPUTECHUNK(bufB, e + 1);
        }

        // ---- selection: two 128-col phases ----
        // thread's keys: cols tx*4..+3 of phase 0 and tx*4..+3 of phase 1
        float4 xxlo = *(const float4*)&xxg[b * Nz + kj0 + tx * 4];
        float4 xxhi = *(const float4*)&xxg[b * Nz + kj0 + 128 + tx * 4];
        float xxa[8] = {xxlo.x, xxlo.y, xxlo.z, xxlo.w,
                        xxhi.x, xxhi.y, xxhi.z, xxhi.w};

#pragma unroll
        for (int h = 0; h < 2; ++h) {
            if (h) __syncthreads();         // phase-0 extract done before rewrite
#pragma unroll
            for (int dq = 0; dq < 8; ++dq) {
                int r = ty * 8 + dq;
                float4 w;
                w.x = 2.f * acc[dq][h * 4 + 0] - xxa[h * 4 + 0];
                w.y = 2.f * acc[dq][h * 4 + 1] - xxa[h * 4 + 1];
                w.z = 2.f * acc[dq][h * 4 + 2] - xxa[h * 4 + 2];
                w.w = 2.f * acc[dq][h * 4 + 3] - xxa[h * 4 + 3];
                *(float4*)&sc[r * 128 + ((tx * 4 + 4 * r) & 127)] = w;
            }
            __syncthreads();

            // scan: lane (srow, part) covers 32 cols
            float wvb = __shfl(wv, lane & 15);
            unsigned m = 0;
#pragma unroll
            for (int g = 0; g < 8; ++g) {
                int col = part * 32 + g * 4;
                float4 v = *(const float4*)&sc[srow * 128 + ((col + 4 * srow) & 127)];
                m |= (unsigned)(v.x > wvb) << (4 * g + 0);
                m |= (unsigned)(v.y > wvb) << (4 * g + 1);
                m |= (unsigned)(v.z > wvb) << (4 * g + 2);
                m |= (unsigned)(v.w > wvb) << (4 * g + 3);
            }
            unsigned long long f = (unsigned long long)m << (32 * (part & 1));
            f |= __shfl_xor(f, 16);
            unsigned long long whi = __shfl(f, 32 + (lane & 15));
            if (lane < 16) {
                EXTRACT(f,   0,  kj0 + h * 128);
                EXTRACT(whi, 64, kj0 + h * 128 + 64);
            }
        }
        // no trailing sync needed: next writes touch bufA/bufB, not sc;
        // sc is next written only after 16 chunk barriers.
    }

    if (lane < 16) {
        size_t base = ((size_t)b * Nz + q0 + orow) * Kz;
#pragma unroll
        for (int s = 0; s < Kz; ++s) idxout[base + s] = ti[s];
    }
#undef LOADCHUNK
#undef WRITECHUNK
#undef COMPUTECHUNK
#undef EXTRACT
}

// ---------------------------------------------------------------------------
// Kernel 3: Y[p][o'] (unchanged)
// ---------------------------------------------------------------------------
__global__ __launch_bounds__(256) void feat_kernel(const float* __restrict__ x,
                                                   const float* __restrict__ W,
                                                   const float* __restrict__ bias,
                                                   float* __restrict__ Y) {
    const int gp0 = blockIdx.x * 64;         // global point index (b*N+n)
    const int b   = gp0 >> 13;
    const int n0  = gp0 & (Nz - 1);
    const int o0  = blockIdx.y * 64;

    __shared__ __align__(16) float xt[128 * 64];   // [c][p]
    __shared__ __align__(16) float wt[128 * 64];   // [c][o']

    const int tid = threadIdx.x;
    const int tx  = tid & 15;
    const int ty  = tid >> 4;

    {
        int li = tid & 63;
        int c0 = tid >> 6;
        const float* xbp = x + (size_t)b * Cz * Nz + n0;
#pragma unroll
        for (int rep = 0; rep < 32; ++rep) {
            int c = c0 + rep * 4;
            xt[c * 64 + li] = xbp[(size_t)c * Nz + li];
        }
    }
    {
        int lo = tid & 63;
        int c0 = tid >> 6;
        int oo = o0 + lo;
#pragma unroll
        for (int rep = 0; rep < 32; ++rep) {
            int c = c0 + rep * 4;
            float w;
            if (oo < 128) w = W[oo * 256 + c] + W[oo * 256 + 128 + c];
            else          w = W[(oo - 128) * 256 + 128 + c];
            wt[c * 64 + lo] = w;
        }
    }
    __syncthreads();

    float acc[4][4];
#pragma unroll
    for (int di = 0; di < 4; ++di)
#pragma unroll
        for (int dj = 0; dj < 4; ++dj) acc[di][dj] = 0.f;

    const int aoff = ty * 4;
    const int boff = tx * 4;
#pragma unroll 8
    for (int c = 0; c < 128; ++c) {
        float4 a  = *(const float4*)&xt[c * 64 + aoff];
        float4 ww = *(const float4*)&wt[c * 64 + boff];
        float av[4] = {a.x, a.y, a.z, a.w};
        float wvv[4] = {ww.x, ww.y, ww.z, ww.w};
#pragma unroll
        for (int di = 0; di < 4; ++di)
#pragma unroll
            for (int dj = 0; dj < 4; ++dj)
                acc[di][dj] = fmaf(av[di], wvv[dj], acc[di][dj]);
    }

    float4 bv = make_float4(0.f, 0.f, 0.f, 0.f);
    if (o0 < 128) bv = *(const float4*)&bias[o0 + tx * 4];
#pragma unroll
    for (int di = 0; di < 4; ++di) {
        float4 r;
        r.x = acc[di][0] + bv.x;
        r.y = acc[di][1] + bv.y;
        r.z = acc[di][2] + bv.z;
        r.w = acc[di][3] + bv.w;
        *(float4*)&Y[(size_t)(gp0 + ty * 4 + di) * 256 + o0 + tx * 4] = r;
    }
}

// ---------------------------------------------------------------------------
// Kernel 4: out[b][o][n] = relu(u[n][o] - min_j v[idx[n][j]][o])  (unchanged)
// ---------------------------------------------------------------------------
__global__ __launch_bounds__(256) void gather_kernel(const int* __restrict__ idxg,
                                                     const float* __restrict__ Y,
                                                     float* __restrict__ out) {
    const int gp0 = blockIdx.x * 64;
    const int b   = gp0 >> 13;
    const int n0  = gp0 & (Nz - 1);

    __shared__ int lidx[64 * 21];
    const int tid = threadIdx.x;
    for (int t = tid; t < 64 * Kz; t += 256) {
        int p = t / Kz, j = t - p * Kz;
        lidx[p * 21 + j] = idxg[(size_t)(gp0 + p) * Kz + j];
    }
    __syncthreads();

    const int p  = tid & 63;
    const int o0 = (tid >> 6) * 32;

    float mn[32];
#pragma unroll
    for (int q = 0; q < 32; ++q) mn[q] = FLT_MAX;

    for (int j = 0; j < Kz; ++j) {
        int m = lidx[p * 21 + j];
        const float4* vr =
            (const float4*)(Y + (size_t)(b * Nz + m) * 256 + 128 + o0);
#pragma unroll
        for (int q = 0; q < 8; ++q) {
            float4 v4 = vr[q];
            mn[4 * q + 0] = fminf(mn[4 * q + 0], v4.x);
            mn[4 * q + 1] = fminf(mn[4 * q + 1], v4.y);
            mn[4 * q + 2] = fminf(mn[4 * q + 2], v4.z);
            mn[4 * q + 3] = fminf(mn[4 * q + 3], v4.w);
        }
    }

    const float4* ur = (const float4*)(Y + (size_t)(gp0 + p) * 256 + o0);
#pragma unroll
    for (int q = 0; q < 8; ++q) {
        float4 u4 = ur[q];
        float r0 = fmaxf(u4.x - mn[4 * q + 0], 0.f);
        float r1 = fmaxf(u4.y - mn[4 * q + 1], 0.f);
        float r2 = fmaxf(u4.z - mn[4 * q + 2], 0.f);
        float r3 = fmaxf(u4.w - mn[4 * q + 3], 0.f);
        size_t ob = ((size_t)b * OUTz + o0 + 4 * q) * Nz + n0 + p;
        out[ob + 0 * Nz] = r0;
        out[ob + 1 * Nz] = r1;
        out[ob + 2 * Nz] = r2;
        out[ob + 3 * Nz] = r3;
    }
}

// ---------------------------------------------------------------------------
extern "C" void kernel_launch(void* const* d_in, const int* in_sizes, int n_in,
                              void* d_out, int out_size, void* d_ws, size_t ws_size,
                              hipStream_t stream) {
    const float* x    = (const float*)d_in[0];
    const float* W    = (const float*)d_in[1];
    const float* bias = (const float*)d_in[2];
    float* out = (float*)d_out;

    char* ws = (char*)d_ws;
    float* xx  = (float*)ws;                       // 128KB  @ 0
    int*   idx = (int*)(ws + (1 << 17));           // 2.5MB  @ 128KB
    float* Y   = (float*)(ws + (4 << 20));         // 32MB   @ 4MB

    xx_kernel<<<dim3(Bz * Nz / 256), dim3(256), 0, stream>>>(x, xx);

    knn_kernel<<<dim3(Nz / 64, Bz), dim3(256), 0, stream>>>(x, xx, idx);

    feat_kernel<<<dim3(Bz * Nz / 64, 4), dim3(256), 0, stream>>>(x, W, bias, Y);

    gather_kernel<<<dim3(Bz * Nz / 64), dim3(256), 0, stream>>>(idx, Y, out);
}

// Round 7
// 1296.355 us; speedup vs baseline: 3.3101x; 1.3482x over previous
//
#include <hip/hip_runtime.h>
#include <float.h>

#define Bz   4
#define Cz   128
#define Nz   8192
#define Kz   20
#define OUTz 128

// ---------------------------------------------------------------------------
// Kernel 1: xx[b*N+n] = sum_c x[b][c][n]^2   (unchanged)
// ---------------------------------------------------------------------------
__global__ __launch_bounds__(256) void xx_kernel(const float* __restrict__ x,
                                                 float* __restrict__ xx) {
    int t = blockIdx.x * 256 + threadIdx.x;          // 0 .. B*N-1
    int b = t >> 13;
    int n = t & (Nz - 1);
    const float* xp = x + (size_t)b * Cz * Nz + n;
    float s = 0.f;
#pragma unroll 8
    for (int c = 0; c < Cz; ++c) {
        float v = xp[(size_t)c * Nz];
        s = fmaf(v, v, s);
    }
    xx[t] = s;
}

// ---------------------------------------------------------------------------
// Kernel 2: fused pairwise-score GEMM + per-row top-20.
// Grid (N/64, B), block 256. Block tile 64q x 256k, per-thread 8x8
// (keys {tx*4..+3, 128+tx*4..+3} -> conflict-free b128 phases).
// LDS 48KB total -> 3 blocks/CU (round 6's 80KB gave ~1 block/CU, latency-
// bound at VALUBusy 42%):
//   Ald  64q x 128c           32KB  (A resident for whole block)
//   buf2 2 x (8c x 256k)      16KB  (double-buffered B chunks)
//   sc   64q x 64col  ALIASES buf2 (disjoint lifetimes; selection runs in
//        4 phases of 64 cols; next tile's chunk-0 sits in registers)
// NO launch_bounds cap beyond 256 (rounds 4/5: caps -> acc spills, 1.5-2.3GB
// scratch traffic). VGPR ~148 -> 3 waves/SIMD, matches 3-block LDS cap.
// Per-pair fp32 chain (ascending c, single fmaf(query,key,acc), 2*acc-xx,
// ascending-j strict-> selection) IDENTICAL to rounds 1-6 -> bit-identical.
// ---------------------------------------------------------------------------
__global__ __launch_bounds__(256) void knn_kernel(const float* __restrict__ x,
                                                  const float* __restrict__ xxg,
                                                  int* __restrict__ idxout) {
    const int b  = blockIdx.y;
    const int q0 = blockIdx.x * 64;

    __shared__ __align__(16) float Ald[128 * 64];   // 32KB [c][q]
    __shared__ __align__(16) float buf2[2 * 8 * 256]; // 16KB
    float* bufA = buf2;            // 8KB [c][k]
    float* bufB = buf2 + 2048;     // 8KB [c][k]
    float* sc   = buf2;            // 16KB [64q][64col rot]  (aliased)

    const int tid  = threadIdx.x;
    const int tx   = tid & 31;      // key group
    const int ty   = tid >> 5;      // query octet (also staging c-row)
    const int lane = tid & 63;
    const int wid  = tid >> 6;

    const float* xb = x + (size_t)b * Cz * Nz;

    // stage A once: Ald[c][q] = x[b][c][q0+q]
    {
        int q4 = (tid & 15) * 4;
        int c0 = tid >> 4;          // 0..15
#pragma unroll
        for (int rep = 0; rep < 8; ++rep) {
            int c = c0 + rep * 16;
            *(float4*)&Ald[c * 64 + q4] =
                *(const float4*)&xb[(size_t)c * Nz + q0 + q4];
        }
    }
    // visibility covered by the first chunk's __syncthreads

    // top-20 state: owner = lane<16 of each wave, row orow
    float tv[Kz];
    int   ti[Kz];
#pragma unroll
    for (int s = 0; s < Kz; ++s) { tv[s] = -FLT_MAX; ti[s] = 0; }
    float wv = -FLT_MAX;
    int wslot = 0;
    const int orow = wid * 16 + lane;            // owner row (lane<16)
    const int srow = wid * 16 + (lane & 15);     // scanned row (all lanes)
    const int part = lane >> 4;                  // 16-col part (0..3)

    float4 st0[2], st1[2];

#define LOADCHUNK(dst, kj, ch)                                                \
    {                                                                         \
        _Pragma("unroll")                                                     \
        for (int i = 0; i < 2; ++i)                                           \
            dst[i] = *(const float4*)&xb[(size_t)((ch) * 8 + ty) * Nz + (kj) + tx * 4 + i * 128]; \
    }

#define WRITECHUNK(src, buf)                                                  \
    {                                                                         \
        _Pragma("unroll")                                                     \
        for (int i = 0; i < 2; ++i)                                           \
            *(float4*)&(buf)[ty * 256 + tx * 4 + i * 128] = src[i];           \
    }

#define COMPUTECHUNK(buf, ch)                                                 \
    {                                                                         \
        _Pragma("unroll")                                                     \
        for (int cc = 0; cc < 8; ++cc) {                                      \
            float4 a0 = *(const float4*)&Ald[((ch) * 8 + cc) * 64 + ty * 8];  \
            float4 a1 = *(const float4*)&Ald[((ch) * 8 + cc) * 64 + ty * 8 + 4]; \
            float4 b0 = *(const float4*)&(buf)[cc * 256 + tx * 4];            \
            float4 b1 = *(const float4*)&(buf)[cc * 256 + 128 + tx * 4];      \
            float av[8] = {a0.x, a0.y, a0.z, a0.w, a1.x, a1.y, a1.z, a1.w};   \
            float bv[8] = {b0.x, b0.y, b0.z, b0.w, b1.x, b1.y, b1.z, b1.w};   \
            _Pragma("unroll")                                                 \
            for (int q = 0; q < 8; ++q) {                                     \
                _Pragma("unroll")                                             \
                for (int k = 0; k < 8; ++k)                                   \
                    acc[q][k] = fmaf(av[q], bv[k], acc[q][k]);                \
            }                                                                 \
        }                                                                     \
    }

#define EXTRACT(pm_, gbase_)                                                  \
    {                                                                         \
        unsigned long long pm = (pm_);                                        \
        while (pm) {                                                          \
            int j = __ffsll(pm) - 1;                                          \
            pm &= pm - 1;                                                     \
            float s = sc[orow * 64 + ((j + 4 * orow) & 63)];                  \
            if (s > wv) {                                                     \
                int gj = (gbase_) + j;                                        \
                _Pragma("unroll")                                             \
                for (int s2 = 0; s2 < Kz; ++s2) {                             \
                    bool hit = (s2 == wslot);                                 \
                    tv[s2] = hit ? s : tv[s2];                                \
                    ti[s2] = hit ? gj : ti[s2];                               \
                }                                                             \
                wv = tv[0]; wslot = 0;                                        \
                _Pragma("unroll")                                             \
                for (int s2 = 1; s2 < Kz; ++s2)                               \
                    if (tv[s2] < wv) { wv = tv[s2]; wslot = s2; }             \
            }                                                                 \
        }                                                                     \
    }

    // prologue: tile 0, chunk 0
    LOADCHUNK(st0, 0, 0);

#pragma unroll 1
    for (int kt = 0; kt < Nz / 256; ++kt) {
        const int kj0 = kt * 256;
        const int kjn = ((kt + 1) & (Nz / 256 - 1)) * 256;

        float acc[8][8];
#pragma unroll
        for (int q = 0; q < 8; ++q)
#pragma unroll
            for (int k = 0; k < 8; ++k) acc[q][k] = 0.f;

#pragma unroll 1
        for (int cp = 0; cp < 8; ++cp) {
            const int e = 2 * cp;
            WRITECHUNK(st0, bufA);
            __syncthreads();
            LOADCHUNK(st1, kj0, e + 1);
            COMPUTECHUNK(bufA, e);
            WRITECHUNK(st1, bufB);
            __syncthreads();
            if (e == 14) { LOADCHUNK(st0, kjn, 0); }
            else         { LOADCHUNK(st0, kj0, e + 2); }
            COMPUTECHUNK(bufB, e + 1);
        }
        __syncthreads();   // bufB reads done before sc (aliased) is written

        // ---- selection: four 64-col phases over the aliased sc tile ----
        float4 xxlo = *(const float4*)&xxg[b * Nz + kj0 + tx * 4];
        float4 xxhi = *(const float4*)&xxg[b * Nz + kj0 + 128 + tx * 4];
        float xxa[8] = {xxlo.x, xxlo.y, xxlo.z, xxlo.w,
                        xxhi.x, xxhi.y, xxhi.z, xxhi.w};
        const int txh = tx >> 4;          // which 64-col half this thread owns
        const int cl0 = (tx & 15) * 4;    // col base within a phase

#pragma unroll
        for (int h = 0; h < 4; ++h) {
            // phase h = global cols [kj0+h*64, kj0+h*64+64)
            if (txh == (h & 1)) {
                const int qs = (h >> 1) * 4;   // acc quad: 0..3 or 4..7
#pragma unroll
                for (int dq = 0; dq < 8; ++dq) {
                    int r = ty * 8 + dq;
                    float4 w;
                    w.x = 2.f * acc[dq][qs + 0] - xxa[qs + 0];
                    w.y = 2.f * acc[dq][qs + 1] - xxa[qs + 1];
                    w.z = 2.f * acc[dq][qs + 2] - xxa[qs + 2];
                    w.w = 2.f * acc[dq][qs + 3] - xxa[qs + 3];
                    *(float4*)&sc[r * 64 + ((cl0 + 4 * r) & 63)] = w;
                }
            }
            __syncthreads();

            // scan: lane (srow, part) covers 16 cols
            float wvb = __shfl(wv, lane & 15);
            unsigned m = 0;
#pragma unroll
            for (int g = 0; g < 4; ++g) {
                int col = part * 16 + g * 4;
                float4 v = *(const float4*)&sc[srow * 64 + ((col + 4 * srow) & 63)];
                m |= (unsigned)(v.x > wvb) << (4 * g + 0);
                m |= (unsigned)(v.y > wvb) << (4 * g + 1);
                m |= (unsigned)(v.z > wvb) << (4 * g + 2);
                m |= (unsigned)(v.w > wvb) << (4 * g + 3);
            }
            unsigned long long f = (unsigned long long)m << (16 * part);
            f |= __shfl_xor(f, 16);
            f |= __shfl_xor(f, 32);
            if (lane < 16) { EXTRACT(f, kj0 + h * 64); }
            __syncthreads();   // extraction done before next write (phase/tile)
        }
    }

    if (lane < 16) {
        size_t base = ((size_t)b * Nz + q0 + orow) * Kz;
#pragma unroll
        for (int s = 0; s < Kz; ++s) idxout[base + s] = ti[s];
    }
#undef LOADCHUNK
#undef WRITECHUNK
#undef COMPUTECHUNK
#undef EXTRACT
}

// ---------------------------------------------------------------------------
// Kernel 3: Y[p][o'] (unchanged)
// ---------------------------------------------------------------------------
__global__ __launch_bounds__(256) void feat_kernel(const float* __restrict__ x,
                                                   const float* __restrict__ W,
                                                   const float* __restrict__ bias,
                                                   float* __restrict__ Y) {
    const int gp0 = blockIdx.x * 64;         // global point index (b*N+n)
    const int b   = gp0 >> 13;
    const int n0  = gp0 & (Nz - 1);
    const int o0  = blockIdx.y * 64;

    __shared__ __align__(16) float xt[128 * 64];   // [c][p]
    __shared__ __align__(16) float wt[128 * 64];   // [c][o']

    const int tid = threadIdx.x;
    const int tx  = tid & 15;
    const int ty  = tid >> 4;

    {
        int li = tid & 63;
        int c0 = tid >> 6;
        const float* xbp = x + (size_t)b * Cz * Nz + n0;
#pragma unroll
        for (int rep = 0; rep < 32; ++rep) {
            int c = c0 + rep * 4;
            xt[c * 64 + li] = xbp[(size_t)c * Nz + li];
        }
    }
    {
        int lo = tid & 63;
        int c0 = tid >> 6;
        int oo = o0 + lo;
#pragma unroll
        for (int rep = 0; rep < 32; ++rep) {
            int c = c0 + rep * 4;
            float w;
            if (oo < 128) w = W[oo * 256 + c] + W[oo * 256 + 128 + c];
            else          w = W[(oo - 128) * 256 + 128 + c];
            wt[c * 64 + lo] = w;
        }
    }
    __syncthreads();

    float acc[4][4];
#pragma unroll
    for (int di = 0; di < 4; ++di)
#pragma unroll
        for (int dj = 0; dj < 4; ++dj) acc[di][dj] = 0.f;

    const int aoff = ty * 4;
    const int boff = tx * 4;
#pragma unroll 8
    for (int c = 0; c < 128; ++c) {
        float4 a  = *(const float4*)&xt[c * 64 + aoff];
        float4 ww = *(const float4*)&wt[c * 64 + boff];
        float av[4] = {a.x, a.y, a.z, a.w};
        float wvv[4] = {ww.x, ww.y, ww.z, ww.w};
#pragma unroll
        for (int di = 0; di < 4; ++di)
#pragma unroll
            for (int dj = 0; dj < 4; ++dj)
                acc[di][dj] = fmaf(av[di], wvv[dj], acc[di][dj]);
    }

    float4 bv = make_float4(0.f, 0.f, 0.f, 0.f);
    if (o0 < 128) bv = *(const float4*)&bias[o0 + tx * 4];
#pragma unroll
    for (int di = 0; di < 4; ++di) {
        float4 r;
        r.x = acc[di][0] + bv.x;
        r.y = acc[di][1] + bv.y;
        r.z = acc[di][2] + bv.z;
        r.w = acc[di][3] + bv.w;
        *(float4*)&Y[(size_t)(gp0 + ty * 4 + di) * 256 + o0 + tx * 4] = r;
    }
}

// ---------------------------------------------------------------------------
// Kernel 4: out[b][o][n] = relu(u[n][o] - min_j v[idx[n][j]][o])  (unchanged)
// ---------------------------------------------------------------------------
__global__ __launch_bounds__(256) void gather_kernel(const int* __restrict__ idxg,
                                                     const float* __restrict__ Y,
                                                     float* __restrict__ out) {
    const int gp0 = blockIdx.x * 64;
    const int b   = gp0 >> 13;
    const int n0  = gp0 & (Nz - 1);

    __shared__ int lidx[64 * 21];
    const int tid = threadIdx.x;
    for (int t = tid; t < 64 * Kz; t += 256) {
        int p = t / Kz, j = t - p * Kz;
        lidx[p * 21 + j] = idxg[(size_t)(gp0 + p) * Kz + j];
    }
    __syncthreads();

    const int p  = tid & 63;
    const int o0 = (tid >> 6) * 32;

    float mn[32];
#pragma unroll
    for (int q = 0; q < 32; ++q) mn[q] = FLT_MAX;

    for (int j = 0; j < Kz; ++j) {
        int m = lidx[p * 21 + j];
        const float4* vr =
            (const float4*)(Y + (size_t)(b * Nz + m) * 256 + 128 + o0);
#pragma unroll
        for (int q = 0; q < 8; ++q) {
            float4 v4 = vr[q];
            mn[4 * q + 0] = fminf(mn[4 * q + 0], v4.x);
            mn[4 * q + 1] = fminf(mn[4 * q + 1], v4.y);
            mn[4 * q + 2] = fminf(mn[4 * q + 2], v4.z);
            mn[4 * q + 3] = fminf(mn[4 * q + 3], v4.w);
        }
    }

    const float4* ur = (const float4*)(Y + (size_t)(gp0 + p) * 256 + o0);
#pragma unroll
    for (int q = 0; q < 8; ++q) {
        float4 u4 = ur[q];
        float r0 = fmaxf(u4.x - mn[4 * q + 0], 0.f);
        float r1 = fmaxf(u4.y - mn[4 * q + 1], 0.f);
        float r2 = fmaxf(u4.z - mn[4 * q + 2], 0.f);
        float r3 = fmaxf(u4.w - mn[4 * q + 3], 0.f);
        size_t ob = ((size_t)b * OUTz + o0 + 4 * q) * Nz + n0 + p;
        out[ob + 0 * Nz] = r0;
        out[ob + 1 * Nz] = r1;
        out[ob + 2 * Nz] = r2;
        out[ob + 3 * Nz] = r3;
    }
}

// ---------------------------------------------------------------------------
extern "C" void kernel_launch(void* const* d_in, const int* in_sizes, int n_in,
                              void* d_out, int out_size, void* d_ws, size_t ws_size,
                              hipStream_t stream) {
    const float* x    = (const float*)d_in[0];
    const float* W    = (const float*)d_in[1];
    const float* bias = (const float*)d_in[2];
    float* out = (float*)d_out;

    char* ws = (char*)d_ws;
    float* xx  = (float*)ws;                       // 128KB  @ 0
    int*   idx = (int*)(ws + (1 << 17));           // 2.5MB  @ 128KB
    float* Y   = (float*)(ws + (4 << 20));         // 32MB   @ 4MB

    xx_kernel<<<dim3(Bz * Nz / 256), dim3(256), 0, stream>>>(x, xx);

    knn_kernel<<<dim3(Nz / 64, Bz), dim3(256), 0, stream>>>(x, xx, idx);

    feat_kernel<<<dim3(Bz * Nz / 64, 4), dim3(256), 0, stream>>>(x, W, bias, Y);

    gather_kernel<<<dim3(Bz * Nz / 64), dim3(256), 0, stream>>>(idx, Y, out);
}